// Round 8
// baseline (313.119 us; speedup 1.0000x reference)
//
#include <hip/hip_runtime.h>
#include <hip/hip_bf16.h>
#include <math.h>

#define B 16
#define N 512
#define L 512
#define DIM 10
#define DM 128
#define H 8
#define DK 16
#define DFF 512
#define LG 3
#define LO 3
#define NEGV -9.0e15f
#define RF 16     // rows per block (ffn/qkv/oproj)
#define AQR 64    // q-rows per attn block
#define KT 64     // keys per attn tile
#define NT (L / KT)

__device__ __forceinline__ float wave_reduce_sum(float v) {
    #pragma unroll
    for (int o = 32; o > 0; o >>= 1) v += __shfl_down(v, o, 64);
    return v;
}

__device__ __forceinline__ float dot16(float4 q0, float4 q1, float4 q2, float4 q3,
                                       float4 k0, float4 k1, float4 k2, float4 k3) {
    return q0.x*k0.x + q0.y*k0.y + q0.z*k0.z + q0.w*k0.w
         + q1.x*k1.x + q1.y*k1.y + q1.z*k1.z + q1.w*k1.w
         + q2.x*k2.x + q2.y*k2.y + q2.z*k2.z + q2.w*k2.w
         + q3.x*k3.x + q3.y*k3.y + q3.z*k3.z + q3.w*k3.w;
}

// ---------------- GNN ----------------

__global__ void k_embed_fp(const int* __restrict__ fing, const float* __restrict__ emb_fp,
                           float* __restrict__ xs) {
    int idx = blockIdx.x * blockDim.x + threadIdx.x;
    if (idx >= B * N * DIM) return;
    int d = idx % DIM;
    int bn = idx / DIM;
    xs[idx] = emb_fp[fing[bn] * DIM + d];
}

__global__ void k_gnn_h(const float* __restrict__ xs, const float* __restrict__ fp_mask,
                        const float* __restrict__ Wg, const float* __restrict__ bg,
                        const float* __restrict__ aatt,
                        float* __restrict__ h, float* __restrict__ s1, float* __restrict__ s2) {
    int bn = blockIdx.x * blockDim.x + threadIdx.x;
    if (bn >= B * N) return;
    float x[DIM];
    #pragma unroll
    for (int d = 0; d < DIM; d++) x[d] = xs[bn * DIM + d];
    float m = fp_mask[bn];
    float a1 = 0.f, a2 = 0.f;
    #pragma unroll
    for (int j = 0; j < DIM; j++) {
        float acc = bg[j];
        #pragma unroll
        for (int d = 0; d < DIM; d++) acc += x[d] * Wg[d * DIM + j];
        acc = fmaxf(acc, 0.f) * m;
        h[bn * DIM + j] = acc;
        a1 += acc * aatt[j];
        a2 += acc * aatt[DIM + j];
    }
    s1[bn] = a1;
    s2[bn] = a2;
}

// 16 lane-groups of 16 lanes; each group owns one row. grid = B*(N/16), 256 thr.
__global__ void k_gnn_att(const float* __restrict__ h, const float* __restrict__ s1,
                          const float* __restrict__ s2, const int* __restrict__ adj,
                          float* __restrict__ xs) {
    int b  = blockIdx.x / (N / 16);
    int rg = blockIdx.x % (N / 16);
    int t = threadIdx.x;
    int g  = t >> 4;   // group 0..15
    int ll = t & 15;   // lane in group
    int i = rg * 16 + g;

    __shared__ float h_s[N * DIM];   // 20KB
    __shared__ float s2_s[N];        // 2KB

    const float* hb = h + (long)b * N * DIM;
    for (int idx = t; idx < N * DIM; idx += 256) h_s[idx] = hb[idx];
    for (int j = t; j < N; j += 256) s2_s[j] = s2[b * N + j];
    __syncthreads();

    float s1v = s1[b * N + i];
    const int* adjrow = adj + ((long)b * N + i) * N;

    float e[32];
    #pragma unroll
    for (int c = 0; c < 32; c++) {
        int j = c * 16 + ll;
        float xsc = s1v + s2_s[j];
        xsc = xsc > 0.f ? xsc : 0.01f * xsc;
        e[c] = (adjrow[j] > 0) ? xsc : NEGV;
    }
    float m = e[0];
    #pragma unroll
    for (int c = 1; c < 32; c++) m = fmaxf(m, e[c]);
    #pragma unroll
    for (int off = 1; off < 16; off <<= 1) m = fmaxf(m, __shfl_xor(m, off, 64));

    float sum = 0.f;
    float a[DIM];
    #pragma unroll
    for (int d = 0; d < DIM; d++) a[d] = 0.f;
    #pragma unroll
    for (int c = 0; c < 32; c++) {
        float p = expf(e[c] - m);
        sum += p;
        int j = c * 16 + ll;
        #pragma unroll
        for (int d = 0; d < DIM; d++) a[d] += p * h_s[j * DIM + d];
    }
    #pragma unroll
    for (int off = 1; off < 16; off <<= 1) {
        sum += __shfl_xor(sum, off, 64);
        #pragma unroll
        for (int d = 0; d < DIM; d++) a[d] += __shfl_xor(a[d], off, 64);
    }
    if (ll < DIM) {
        float av = a[0];
        if (ll == 1) av = a[1]; else if (ll == 2) av = a[2]; else if (ll == 3) av = a[3];
        else if (ll == 4) av = a[4]; else if (ll == 5) av = a[5]; else if (ll == 6) av = a[6];
        else if (ll == 7) av = a[7]; else if (ll == 8) av = a[8]; else if (ll == 9) av = a[9];
        xs[((long)b * N + i) * DIM + ll] += av / sum;
    }
}

__global__ void k_compound(const float* __restrict__ xs, const float* __restrict__ fp_mask,
                           const float* __restrict__ Watt, const float* __restrict__ batt,
                           float* __restrict__ compound, float* __restrict__ hc) {
    int b = blockIdx.x;
    int t = threadIdx.x;  // 256
    int wid = t >> 6, lane = t & 63;
    float lacc[DIM];
    #pragma unroll
    for (int d = 0; d < DIM; d++) lacc[d] = 0.f;
    for (int n = t; n < N; n += 256) {
        float m = fp_mask[b * N + n];
        #pragma unroll
        for (int d = 0; d < DIM; d++) lacc[d] += xs[((long)b * N + n) * DIM + d] * m;
    }
    __shared__ float red[4][DIM];
    __shared__ float comp_s[DIM];
    #pragma unroll
    for (int d = 0; d < DIM; d++) lacc[d] = wave_reduce_sum(lacc[d]);
    if (lane == 0) {
        #pragma unroll
        for (int d = 0; d < DIM; d++) red[wid][d] = lacc[d];
    }
    __syncthreads();
    if (t < DIM) {
        float c = (red[0][t] + red[1][t] + red[2][t] + red[3][t]) / (float)N;
        compound[b * DIM + t] = c;
        comp_s[t] = c;
    }
    __syncthreads();
    if (t < DIM) {
        float acc = batt[t];
        #pragma unroll
        for (int e = 0; e < DIM; e++) acc += comp_s[e] * Watt[e * DIM + t];
        hc[b * DIM + t] = fmaxf(acc, 0.f);
    }
}

// ---------------- Transformer ----------------

__global__ void k_pe(float* __restrict__ pe) {
    int idx = blockIdx.x * blockDim.x + threadIdx.x;
    if (idx >= L * DM) return;
    int d = idx % DM, l = idx / DM;
    int k = d >> 1;
    double div = exp((double)(2 * k) * (-log(10000.0) / (double)DM));
    double ang = (double)l * div;
    pe[idx] = (d & 1) ? (float)cos(ang) : (float)sin(ang);
}

__global__ void k_embed_word(const int* __restrict__ words, const float* __restrict__ emb,
                             const float* __restrict__ pe, float* __restrict__ x) {
    long idx = (long)blockIdx.x * blockDim.x + threadIdx.x;
    if (idx >= (long)B * L * DM) return;
    int d = idx % DM;
    long bl = idx / DM;
    int l = (int)(bl % L);
    x[idx] = emb[(long)words[bl] * DM + d] * sqrtf(128.0f) + pe[l * DM + d];
}

__global__ void k_layernorm(const float* __restrict__ x, const float* __restrict__ g,
                            const float* __restrict__ bb, float* __restrict__ out) {
    int row = blockIdx.x;
    int t = threadIdx.x;  // 128
    int wid = t >> 6, lane = t & 63;
    float v = x[(long)row * DM + t];
    float s = wave_reduce_sum(v);
    __shared__ float r2[2], r3[2];
    if (lane == 0) r2[wid] = s;
    __syncthreads();
    float mean = (r2[0] + r2[1]) / (float)DM;
    float dv = v - mean;
    float q = wave_reduce_sum(dv * dv);
    if (lane == 0) r3[wid] = q;
    __syncthreads();
    float sd = sqrtf((r3[0] + r3[1]) / (float)(DM - 1)) + 1e-6f;
    out[(long)row * DM + t] = g[t] * dv / sd + bb[t];
}

// 16 rows per block, 384 threads: thread = (proj, out-col)
__global__ void k_qkv(const float* __restrict__ xn,
                      const float* __restrict__ Wq, const float* __restrict__ bq,
                      const float* __restrict__ Wk, const float* __restrict__ bk,
                      const float* __restrict__ Wv, const float* __restrict__ bv,
                      float* __restrict__ q, float* __restrict__ k, float* __restrict__ v) {
    long row0 = (long)blockIdx.x * RF;
    int t = threadIdx.x;  // 384
    __shared__ float xs_s[RF * DM];
    for (int i = t; i < RF * DM; i += 384) xs_s[i] = xn[row0 * DM + i];
    __syncthreads();
    int proj = t / DM;
    int j = t % DM;
    const float* W    = proj == 0 ? Wq : (proj == 1 ? Wk : Wv);
    const float* bias = proj == 0 ? bq : (proj == 1 ? bk : bv);
    float* out        = proj == 0 ? q  : (proj == 1 ? k  : v);
    float acc[RF];
    #pragma unroll
    for (int r = 0; r < RF; r++) acc[r] = bias[j];
    for (int d = 0; d < DM; d++) {
        float w = W[d * DM + j];
        #pragma unroll
        for (int r = 0; r < RF; r++) acc[r] += xs_s[r * DM + d] * w;
    }
    #pragma unroll
    for (int r = 0; r < RF; r++) {
        long row = row0 + r;
        int b = (int)(row / L), l = (int)(row % L);
        out[(((long)b * H + j / DK) * L + l) * DK + (j % DK)] = acc[r];
    }
}

// GEMM-tiled flash attention. grid = B*H*(L/64), 256 threads (4 waves).
// Thread = (2 q-rows: qg = t>>3, 8 keys/tile: kg = t&7). Q frag + O acc in
// registers; K/V/mask double-buffered in LDS with XOR-swizzled chunk layout
// (kg-stride 512B is bank-aligned -> swizzle chunk by (key>>3)&3 -> <=2-way).
// Scores are lane-local: only the tile-max is shuffle-reduced (offs 1,2,4
// within the 8 lanes sharing a row pair) so rescales stay uniform; O / ss
// partials are summed across those lanes once at the end.
__global__ void __launch_bounds__(256, 4)
k_attn(const float* __restrict__ q, const float* __restrict__ k,
       const float* __restrict__ v, const float* __restrict__ wmask,
       float* __restrict__ attnout) {
    int blk = blockIdx.x;
    int qc = blk % (L / AQR);
    int bh = blk / (L / AQR);
    int b = bh / H, hh = bh % H;
    int t = threadIdx.x;   // 256
    int qg = t >> 3;       // 0..31 -> rows 2qg, 2qg+1
    int kg = t & 7;        // 0..7  -> keys 8kg..8kg+7 within tile

    __shared__ float kbuf[2][KT][DK];   // 8KB
    __shared__ float vbuf[2][KT][DK];   // 8KB
    __shared__ float mbuf[2][KT];       // 512B (additive mask: 0 or -1e9)

    const float4* kb4 = (const float4*)(k + (long)bh * L * DK);
    const float4* vb4 = (const float4*)(v + (long)bh * L * DK);
    const float*  wm  = wmask + (long)b * L;

    // Q fragment: 2 rows x 16 dims, pre-scaled by 1/sqrt(DK)
    int row0 = qc * AQR + 2 * qg;
    const float4* qp = (const float4*)(q + ((long)bh * L + row0) * DK);
    float4 qa[4], qb[4];
    #pragma unroll
    for (int i = 0; i < 4; i++) {
        qa[i] = qp[i];     qb[i] = qp[4 + i];
        qa[i].x *= 0.25f; qa[i].y *= 0.25f; qa[i].z *= 0.25f; qa[i].w *= 0.25f;
        qb[i].x *= 0.25f; qb[i].y *= 0.25f; qb[i].z *= 0.25f; qb[i].w *= 0.25f;
    }

    // staging helper indices: thread t handles float4 #t of the 64x16 tile
    int skey = t >> 2;             // key this thread stages
    int spart = t & 3;             // 16B chunk within key row
    int sphys = spart ^ ((skey >> 3) & 3);   // swizzled chunk

    // ---- prologue: stage tile 0 ----
    {
        float4 kr = kb4[t];
        float4 vr = vb4[t];
        ((float4*)&kbuf[0][skey][0])[sphys] = kr;
        ((float4*)&vbuf[0][skey][0])[sphys] = vr;
        if (t < KT) mbuf[0][t] = (wm[t] > 0.f) ? 0.f : -1e9f;
    }
    __syncthreads();

    float m0 = -1e30f, m1 = -1e30f, ss0 = 0.f, ss1 = 0.f;
    float4 o0[4], o1[4];
    #pragma unroll
    for (int i = 0; i < 4; i++) {
        o0[i] = make_float4(0.f, 0.f, 0.f, 0.f);
        o1[i] = make_float4(0.f, 0.f, 0.f, 0.f);
    }

    int sw = kg & 3;   // read-side swizzle: (key>>3)&3 == kg for this thread's keys
    int cur = 0;
    for (int tt = 0; tt < NT; tt++) {
        // issue next tile's global loads (latency hides under compute)
        float4 kr2, vr2;
        float mr2 = 1.f;
        if (tt < NT - 1) {
            long base = (long)(tt + 1) * KT * 4;
            kr2 = kb4[base + t];
            vr2 = vb4[base + t];
            if (t < KT) mr2 = wm[(tt + 1) * KT + t];
        }

        // ---- QK^T for this thread's 8 keys ----
        float s0[8], s1[8];
        #pragma unroll
        for (int kk = 0; kk < 8; kk++) {
            const float4* kp = (const float4*)&kbuf[cur][kg * 8 + kk][0];
            float4 k0 = kp[0 ^ sw], k1 = kp[1 ^ sw], k2 = kp[2 ^ sw], k3 = kp[3 ^ sw];
            s0[kk] = dot16(qa[0], qa[1], qa[2], qa[3], k0, k1, k2, k3);
            s1[kk] = dot16(qb[0], qb[1], qb[2], qb[3], k0, k1, k2, k3);
        }
        {
            const float4* mp = (const float4*)&mbuf[cur][kg * 8];
            float4 ma = mp[0], mb_ = mp[1];
            s0[0] += ma.x;  s1[0] += ma.x;   s0[1] += ma.y;  s1[1] += ma.y;
            s0[2] += ma.z;  s1[2] += ma.z;   s0[3] += ma.w;  s1[3] += ma.w;
            s0[4] += mb_.x; s1[4] += mb_.x;  s0[5] += mb_.y; s1[5] += mb_.y;
            s0[6] += mb_.z; s1[6] += mb_.z;  s0[7] += mb_.w; s1[7] += mb_.w;
        }

        // ---- tile max (uniform across the 8 row-sharing lanes) ----
        float cm0 = fmaxf(fmaxf(fmaxf(s0[0], s0[1]), fmaxf(s0[2], s0[3])),
                          fmaxf(fmaxf(s0[4], s0[5]), fmaxf(s0[6], s0[7])));
        float cm1 = fmaxf(fmaxf(fmaxf(s1[0], s1[1]), fmaxf(s1[2], s1[3])),
                          fmaxf(fmaxf(s1[4], s1[5]), fmaxf(s1[6], s1[7])));
        cm0 = fmaxf(cm0, __shfl_xor(cm0, 1, 64));
        cm0 = fmaxf(cm0, __shfl_xor(cm0, 2, 64));
        cm0 = fmaxf(cm0, __shfl_xor(cm0, 4, 64));
        cm1 = fmaxf(cm1, __shfl_xor(cm1, 1, 64));
        cm1 = fmaxf(cm1, __shfl_xor(cm1, 2, 64));
        cm1 = fmaxf(cm1, __shfl_xor(cm1, 4, 64));

        float mn0 = fmaxf(m0, cm0), mn1 = fmaxf(m1, cm1);
        float sc0 = __expf(m0 - mn0), sc1 = __expf(m1 - mn1);
        m0 = mn0; m1 = mn1;

        float pls0 = 0.f, pls1 = 0.f;
        #pragma unroll
        for (int kk = 0; kk < 8; kk++) {
            s0[kk] = __expf(s0[kk] - mn0); pls0 += s0[kk];
            s1[kk] = __expf(s1[kk] - mn1); pls1 += s1[kk];
        }
        ss0 = ss0 * sc0 + pls0;
        ss1 = ss1 * sc1 + pls1;
        #pragma unroll
        for (int i = 0; i < 4; i++) {
            o0[i].x *= sc0; o0[i].y *= sc0; o0[i].z *= sc0; o0[i].w *= sc0;
            o1[i].x *= sc1; o1[i].y *= sc1; o1[i].z *= sc1; o1[i].w *= sc1;
        }

        // ---- PV ----
        #pragma unroll
        for (int kk = 0; kk < 8; kk++) {
            const float4* vp = (const float4*)&vbuf[cur][kg * 8 + kk][0];
            float4 v0 = vp[0 ^ sw], v1 = vp[1 ^ sw], v2 = vp[2 ^ sw], v3 = vp[3 ^ sw];
            float p0 = s0[kk], p1 = s1[kk];
            o0[0].x += p0*v0.x; o0[0].y += p0*v0.y; o0[0].z += p0*v0.z; o0[0].w += p0*v0.w;
            o0[1].x += p0*v1.x; o0[1].y += p0*v1.y; o0[1].z += p0*v1.z; o0[1].w += p0*v1.w;
            o0[2].x += p0*v2.x; o0[2].y += p0*v2.y; o0[2].z += p0*v2.z; o0[2].w += p0*v2.w;
            o0[3].x += p0*v3.x; o0[3].y += p0*v3.y; o0[3].z += p0*v3.z; o0[3].w += p0*v3.w;
            o1[0].x += p1*v0.x; o1[0].y += p1*v0.y; o1[0].z += p1*v0.z; o1[0].w += p1*v0.w;
            o1[1].x += p1*v1.x; o1[1].y += p1*v1.y; o1[1].z += p1*v1.z; o1[1].w += p1*v1.w;
            o1[2].x += p1*v2.x; o1[2].y += p1*v2.y; o1[2].z += p1*v2.z; o1[2].w += p1*v2.w;
            o1[3].x += p1*v3.x; o1[3].y += p1*v3.y; o1[3].z += p1*v3.z; o1[3].w += p1*v3.w;
        }

        // ---- write prefetched tile into the other buffer ----
        if (tt < NT - 1) {
            ((float4*)&kbuf[cur ^ 1][skey][0])[sphys] = kr2;
            ((float4*)&vbuf[cur ^ 1][skey][0])[sphys] = vr2;
            if (t < KT) mbuf[cur ^ 1][t] = (mr2 > 0.f) ? 0.f : -1e9f;
        }
        __syncthreads();
        cur ^= 1;
    }

    // ---- merge partials across the 8 lanes sharing this row pair ----
    #pragma unroll
    for (int off = 1; off <= 4; off <<= 1) {
        ss0 += __shfl_xor(ss0, off, 64);
        ss1 += __shfl_xor(ss1, off, 64);
        #pragma unroll
        for (int i = 0; i < 4; i++) {
            o0[i].x += __shfl_xor(o0[i].x, off, 64);
            o0[i].y += __shfl_xor(o0[i].y, off, 64);
            o0[i].z += __shfl_xor(o0[i].z, off, 64);
            o0[i].w += __shfl_xor(o0[i].w, off, 64);
            o1[i].x += __shfl_xor(o1[i].x, off, 64);
            o1[i].y += __shfl_xor(o1[i].y, off, 64);
            o1[i].z += __shfl_xor(o1[i].z, off, 64);
            o1[i].w += __shfl_xor(o1[i].w, off, 64);
        }
    }

    // lane kg writes (row = kg>>2, quad = kg&3)
    int rsel = kg >> 2, qsel = kg & 3;
    float4 t0 = (qsel == 0) ? o0[0] : (qsel == 1) ? o0[1] : (qsel == 2) ? o0[2] : o0[3];
    float4 t1 = (qsel == 0) ? o1[0] : (qsel == 1) ? o1[1] : (qsel == 2) ? o1[2] : o1[3];
    float4 ov = rsel ? t1 : t0;
    float inv = 1.f / (rsel ? ss1 : ss0);
    float4* outp = (float4*)(attnout + ((long)b * L + (row0 + rsel)) * DM + hh * DK);
    outp[qsel] = make_float4(ov.x * inv, ov.y * inv, ov.z * inv, ov.w * inv);
}

// x += attnout @ Wo + bo ; 16 rows/block, 128 threads
__global__ void k_oproj(const float* __restrict__ attnout, const float* __restrict__ Wo,
                        const float* __restrict__ bo, float* __restrict__ x) {
    long row0 = (long)blockIdx.x * RF;
    int t = threadIdx.x;  // 128
    __shared__ float a_s[RF * DM];
    for (int i = t; i < RF * DM; i += 128) a_s[i] = attnout[row0 * DM + i];
    __syncthreads();
    float acc[RF];
    #pragma unroll
    for (int r = 0; r < RF; r++) acc[r] = bo[t];
    for (int d = 0; d < DM; d++) {
        float w = Wo[d * DM + t];
        #pragma unroll
        for (int r = 0; r < RF; r++) acc[r] += a_s[r * DM + d] * w;
    }
    #pragma unroll
    for (int r = 0; r < RF; r++) x[(row0 + r) * DM + t] += acc[r];
}

// fused FFN: x += relu(xn@W1+b1)@W2+b2 ; 16 rows/block, 512 threads
__global__ void k_ffn(const float* __restrict__ xn, const float* __restrict__ W1,
                      const float* __restrict__ b1, const float* __restrict__ W2,
                      const float* __restrict__ b2, float* __restrict__ x) {
    long row0 = (long)blockIdx.x * RF;
    int t = threadIdx.x;  // 512
    __shared__ float xs_s[RF * DM];    // 8KB
    __shared__ float h_s[RF * DFF];    // 32KB
    for (int i = t; i < RF * DM; i += 512) xs_s[i] = xn[row0 * DM + i];
    __syncthreads();
    {
        float acc[RF];
        #pragma unroll
        for (int r = 0; r < RF; r++) acc[r] = b1[t];
        for (int d = 0; d < DM; d++) {
            float w = W1[d * DFF + t];
            #pragma unroll
            for (int r = 0; r < RF; r++) acc[r] += xs_s[r * DM + d] * w;
        }
        #pragma unroll
        for (int r = 0; r < RF; r++) h_s[r * DFF + t] = fmaxf(acc[r], 0.f);
    }
    __syncthreads();
    int col = t & 127, rq = t >> 7;   // rq uniform per wave
    float acc2[4];
    #pragma unroll
    for (int rr = 0; rr < 4; rr++) acc2[rr] = b2[col];
    for (int f = 0; f < DFF; f++) {
        float w = W2[f * DM + col];
        #pragma unroll
        for (int rr = 0; rr < 4; rr++) acc2[rr] += h_s[(rq * 4 + rr) * DFF + f] * w;
    }
    #pragma unroll
    for (int rr = 0; rr < 4; rr++) x[(row0 + rq * 4 + rr) * DM + col] += acc2[rr];
}

// lnf -> relu -> Wtout -> Watt/relu -> hp ; per row, 128 threads
__global__ void k_lnf_hp(const float* __restrict__ x, const float* __restrict__ g,
                         const float* __restrict__ bb, const float* __restrict__ Wtout,
                         const float* __restrict__ btout, const float* __restrict__ Watt,
                         const float* __restrict__ batt, float* __restrict__ hp) {
    int row = blockIdx.x;
    int t = threadIdx.x;  // 128
    int wid = t >> 6, lane = t & 63;
    float v = x[(long)row * DM + t];
    float s = wave_reduce_sum(v);
    __shared__ float r2[2], r3[2];
    if (lane == 0) r2[wid] = s;
    __syncthreads();
    float mean = (r2[0] + r2[1]) / (float)DM;
    float dv = v - mean;
    float qq = wave_reduce_sum(dv * dv);
    if (lane == 0) r3[wid] = qq;
    __syncthreads();
    float sd = sqrtf((r3[0] + r3[1]) / (float)(DM - 1)) + 1e-6f;
    float xnv = g[t] * dv / sd + bb[t];
    __shared__ float rrelu[DM];
    rrelu[t] = fmaxf(xnv, 0.f);
    __syncthreads();
    __shared__ float wv_s[DIM];
    if (t < DIM) {
        float acc = btout[t];
        for (int d = 0; d < DM; d++) acc += rrelu[d] * Wtout[d * DIM + t];
        wv_s[t] = acc;
    }
    __syncthreads();
    if (t < DIM) {
        float acc = batt[t];
        #pragma unroll
        for (int e = 0; e < DIM; e++) acc += wv_s[e] * Watt[e * DIM + t];
        hp[(long)row * DIM + t] = fmaxf(acc, 0.f);
    }
}

// final: w = tanh(hc . hp_l) ; protein = mean(w * hp) ; 3-layer MLP ; output.
__global__ void k_final(const float* __restrict__ hp, const float* __restrict__ hc,
                        const float* __restrict__ compound, const float* __restrict__ Wout,
                        const float* __restrict__ bout, const float* __restrict__ Wint,
                        const float* __restrict__ bint, float* __restrict__ out) {
    int b = blockIdx.x;
    int t = threadIdx.x;  // 256
    int wid = t >> 6, lane = t & 63;

    __shared__ float wout_s[LO * 2 * DIM * 2 * DIM];  // 1200 floats
    __shared__ float bout_s[LO * 2 * DIM];
    __shared__ float wint_s[2 * DIM * 2];
    __shared__ float bint_s[2];
    __shared__ float hc_s[DIM];
    __shared__ float red[4][DIM];
    __shared__ float cat_s[2 * DIM];
    __shared__ float tmp_s[2 * DIM];

    for (int i = t; i < LO * 2 * DIM * 2 * DIM; i += 256) wout_s[i] = Wout[i];
    for (int i = t; i < LO * 2 * DIM; i += 256) bout_s[i] = bout[i];
    for (int i = t; i < 2 * DIM * 2; i += 256) wint_s[i] = Wint[i];
    if (t < 2) bint_s[t] = bint[t];
    if (t < DIM) hc_s[t] = hc[b * DIM + t];
    __syncthreads();

    float lacc[DIM];
    #pragma unroll
    for (int e = 0; e < DIM; e++) lacc[e] = 0.f;
    for (int l = t; l < L; l += 256) {
        const float* hpl = hp + ((long)b * L + l) * DIM;
        float hv[DIM];
        float dot = 0.f;
        #pragma unroll
        for (int e = 0; e < DIM; e++) { hv[e] = hpl[e]; dot += hc_s[e] * hv[e]; }
        float w = tanhf(dot);
        #pragma unroll
        for (int e = 0; e < DIM; e++) lacc[e] += w * hv[e];
    }
    #pragma unroll
    for (int e = 0; e < DIM; e++) lacc[e] = wave_reduce_sum(lacc[e]);
    if (lane == 0) {
        #pragma unroll
        for (int e = 0; e < DIM; e++) red[wid][e] = lacc[e];
    }
    __syncthreads();
    if (t < DIM) {
        cat_s[t] = compound[b * DIM + t];
        cat_s[DIM + t] = (red[0][t] + red[1][t] + red[2][t] + red[3][t]) / (float)L;
    }
    __syncthreads();

    for (int j = 0; j < LO; j++) {
        float acc = 0.f;
        if (t < 2 * DIM) {
            acc = bout_s[j * 2 * DIM + t];
            #pragma unroll
            for (int e = 0; e < 2 * DIM; e++)
                acc += cat_s[e] * wout_s[j * 2 * DIM * 2 * DIM + e * 2 * DIM + t];
            acc = fmaxf(acc, 0.f);
            tmp_s[t] = acc;
        }
        __syncthreads();
        if (t < 2 * DIM) cat_s[t] = tmp_s[t];
        __syncthreads();
    }
    if (t < 2) {
        float o = bint_s[t];
        #pragma unroll
        for (int e = 0; e < 2 * DIM; e++) o += cat_s[e] * wint_s[e * 2 + t];
        out[b * 2 + t] = o;
    }
}

extern "C" void kernel_launch(void* const* d_in, const int* in_sizes, int n_in,
                              void* d_out, int out_size, void* d_ws, size_t ws_size,
                              hipStream_t stream) {
    (void)in_sizes; (void)n_in; (void)out_size; (void)ws_size;
    const int*   fingerprints = (const int*)d_in[0];
    const float* fp_mask      = (const float*)d_in[1];
    const int*   adjacency    = (const int*)d_in[2];
    const int*   words        = (const int*)d_in[3];
    const float* words_mask   = (const float*)d_in[4];
    const float* emb_fp       = (const float*)d_in[5];
    const float* emb_word     = (const float*)d_in[6];
    const float* Wg   = (const float*)d_in[7];
    const float* bg   = (const float*)d_in[8];
    const float* attn_a = (const float*)d_in[9];
    const float* Wq = (const float*)d_in[10];
    const float* bq = (const float*)d_in[11];
    const float* Wk = (const float*)d_in[12];
    const float* bk = (const float*)d_in[13];
    const float* Wv = (const float*)d_in[14];
    const float* bv = (const float*)d_in[15];
    const float* Wo = (const float*)d_in[16];
    const float* bo = (const float*)d_in[17];
    const float* ln1_g = (const float*)d_in[18];
    const float* ln1_b = (const float*)d_in[19];
    const float* ln2_g = (const float*)d_in[20];
    const float* ln2_b = (const float*)d_in[21];
    const float* lnf_g = (const float*)d_in[22];
    const float* lnf_b = (const float*)d_in[23];
    const float* W1 = (const float*)d_in[24];
    const float* b1 = (const float*)d_in[25];
    const float* W2 = (const float*)d_in[26];
    const float* b2 = (const float*)d_in[27];
    const float* Wtout = (const float*)d_in[28];
    const float* btout = (const float*)d_in[29];
    const float* Watt  = (const float*)d_in[30];
    const float* batt  = (const float*)d_in[31];
    const float* Wout  = (const float*)d_in[32];
    const float* bout  = (const float*)d_in[33];
    const float* Wint  = (const float*)d_in[34];
    const float* bint  = (const float*)d_in[35];
    float* out = (float*)d_out;

    float* w = (float*)d_ws;
    float* xs = w;        w += B * N * DIM;
    float* h  = w;        w += B * N * DIM;
    float* s1 = w;        w += B * N;
    float* s2 = w;        w += B * N;
    float* compound = w;  w += B * DIM;
    float* hc = w;        w += B * DIM;
    float* pe = w;        w += L * DM;
    float* x  = w;        w += (long)B * L * DM;
    float* xn = w;        w += (long)B * L * DM;
    float* qb = w;        w += (long)B * H * L * DK;
    float* kb = w;        w += (long)B * H * L * DK;
    float* vb = w;        w += (long)B * H * L * DK;
    float* attnout = w;   w += (long)B * L * DM;
    float* hp = w;        w += (long)B * L * DIM;

    // ---- GNN ----
    k_embed_fp<<<(B * N * DIM + 255) / 256, 256, 0, stream>>>(fingerprints, emb_fp, xs);
    for (int i = 0; i < LG; i++) {
        k_gnn_h<<<(B * N + 255) / 256, 256, 0, stream>>>(
            xs, fp_mask, Wg + i * DIM * DIM, bg + i * DIM, attn_a + i * 2 * DIM, h, s1, s2);
        k_gnn_att<<<B * (N / 16), 256, 0, stream>>>(h, s1, s2, adjacency, xs);
    }
    k_compound<<<B, 256, 0, stream>>>(xs, fp_mask, Watt, batt, compound, hc);

    // ---- Transformer ----
    k_pe<<<(L * DM + 255) / 256, 256, 0, stream>>>(pe);
    k_embed_word<<<(B * L * DM + 255) / 256, 256, 0, stream>>>(words, emb_word, pe, x);
    k_layernorm<<<B * L, DM, 0, stream>>>(x, ln1_g, ln1_b, xn);
    k_qkv<<<B * L / RF, 3 * DM, 0, stream>>>(xn, Wq, bq, Wk, bk, Wv, bv, qb, kb, vb);
    k_attn<<<B * H * (L / AQR), 256, 0, stream>>>(qb, kb, vb, words_mask, attnout);
    k_oproj<<<B * L / RF, DM, 0, stream>>>(attnout, Wo, bo, x);
    k_layernorm<<<B * L, DM, 0, stream>>>(x, ln2_g, ln2_b, xn);
    k_ffn<<<B * L / RF, DFF, 0, stream>>>(xn, W1, b1, W2, b2, x);
    k_lnf_hp<<<B * L, DM, 0, stream>>>(x, lnf_g, lnf_b, Wtout, btout, Watt, batt, hp);
    k_final<<<B, 256, 0, stream>>>(hp, hc, compound, Wout, bout, Wint, bint, out);
}